// Round 13
// baseline (237.413 us; speedup 1.0000x reference)
//
#include <hip/hip_runtime.h>
#include <math.h>

#define B_   8
#define CIN  64
#define N_   3136
#define DIN  576
#define CO   128
#define EPS  1e-5f
// 1/sqrt(128) * log2(e): QK^T lands in log2 domain -> v_exp_f32 is exp2
#define QSCALE2 0.1275174447f

typedef __attribute__((ext_vector_type(8))) short sh8;     // 8 bf16 (4 VGPRs)
typedef __attribute__((ext_vector_type(16))) float fx16;   // MFMA 32x32 accum
typedef __attribute__((ext_vector_type(4))) unsigned int ux4;

__device__ __forceinline__ float gelu_exact(float x) {
    return 0.5f * x * (1.0f + erff(x * 0.7071067811865475f));
}
__device__ __forceinline__ unsigned short f2bf(float f) {   // RN-even f32->bf16
    unsigned u = __float_as_uint(f);
    u += 0x7fffu + ((u >> 16) & 1u);
    return (unsigned short)(u >> 16);
}
__device__ __forceinline__ unsigned pack2(float a, float b) {
    return (unsigned)f2bf(a) | ((unsigned)f2bf(b) << 16);
}
__device__ __forceinline__ unsigned cvtpk(float a, float b) {
    unsigned r;
    asm("v_cvt_pk_bf16_f32 %0, %1, %2" : "=v"(r) : "v"(a), "v"(b));
    return r;
}
__device__ __forceinline__ float exp2v(float x) {           // D = 2^S0
    float r;
    asm("v_exp_f32 %0, %1" : "=v"(r) : "v"(x));
    return r;
}

// ---------------- K0a: pack Wq|Wk|Wv -> pre-swizzled bf16 LDS image ----------------
__global__ __launch_bounds__(256) void wprep_kernel(
    const float* __restrict__ Wq, const float* __restrict__ Wk,
    const float* __restrict__ Wv, unsigned short* __restrict__ wimg)
{
    int id = blockIdx.x * 256 + threadIdx.x;          // 110592 u32 elements
    int col = id % 384;
    int k2  = id / 384;                               // 0..287
    int k   = 2 * k2;
    int s   = k >> 6;
    int kk  = k & 63;
    int t   = col >> 7, c = col & 127;
    const float* W = (t == 0) ? Wq : (t == 1) ? Wk : Wv;
    float v0 = W[(size_t)k * CO + c];
    float v1 = W[(size_t)(k + 1) * CO + c];
    char* dst = (char*)wimg + (size_t)s * 49152 + col * 128 + ((kk * 2) ^ ((col & 7) << 4));
    *reinterpret_cast<unsigned*>(dst) = pack2(v0, v1);
}

// ---------------- K0b: x -> zero-padded image xpad[B][CIN][58][58] ----------------
__global__ __launch_bounds__(256) void pad_kernel(
    const float* __restrict__ x, float* __restrict__ xpad)
{
    int id = blockIdx.x * 256 + threadIdx.x;          // 1,722,368 elements
    int j  = id % 58;
    int i  = (id / 58) % 58;
    int bc = id / 3364;                               // b*64+c
    float v = 0.f;
    if (i >= 1 && i <= 56 && j >= 1 && j <= 56)
        v = x[((size_t)bc * 56 + (i - 1)) * 56 + (j - 1)];
    xpad[id] = v;
}

// ---------------- K1: im2col + QKV MFMA GEMM + bias + LayerNorm -> bf16 ----------------
__global__ __launch_bounds__(256, 2) void qkv_kernel(
    const float* __restrict__ xpad, const unsigned short* __restrict__ wimg,
    const float* __restrict__ bq, const float* __restrict__ gq, const float* __restrict__ btq,
    const float* __restrict__ bk, const float* __restrict__ gk, const float* __restrict__ btk,
    const float* __restrict__ bv, const float* __restrict__ gv, const float* __restrict__ btv,
    unsigned short* __restrict__ qo, unsigned short* __restrict__ ko,
    unsigned short* __restrict__ vt)
{
    __shared__ alignas(16) char Alds[8192];    // [64 rows][64 k] bf16, swizzled
    __shared__ alignas(16) char Wlds[49152];   // [384 cols][64 k] bf16, swizzled image
    const int b   = blockIdx.x & 7;
    const int n0  = (blockIdx.x >> 3) * 64;
    const int tid = threadIdx.x;
    const int w   = tid >> 6;
    const int l   = tid & 63;
    const int h   = l >> 5;
    const int lq  = l & 31;
    const int key = (lq & 7) << 4;

    const int n  = n0 + l;
    const int oh = n / 56, ow = n - 56 * oh;
    const int xbase = b * CIN * 3364 + oh * 58 + ow;   // + c*3364 + kh*58 + kw

    fx16 acc[2][3];
    #pragma unroll
    for (int mt = 0; mt < 2; ++mt)
        #pragma unroll
        for (int cb = 0; cb < 3; ++cb)
            #pragma unroll
            for (int e = 0; e < 16; ++e) acc[mt][cb][e] = 0.f;

    float xc[16], xn[16];

    auto loadx = [&](int s, float* xv) {
        #pragma unroll
        for (int i = 0; i < 8; ++i) {
            int k2 = w + 4 * i;
            int d0 = s * 64 + 2 * k2, d1 = d0 + 1;
            int c0 = d0 / 9, r90 = d0 - 9 * c0;
            int kh0 = r90 / 3, kw0 = r90 - 3 * kh0;
            int c1 = d1 / 9, r91 = d1 - 9 * c1;
            int kh1 = r91 / 3, kw1 = r91 - 3 * kh1;
            xv[2 * i]     = xpad[xbase + c0 * 3364 + kh0 * 58 + kw0];
            xv[2 * i + 1] = xpad[xbase + c1 * 3364 + kh1 * 58 + kw1];
        }
    };

    loadx(0, xc);
    for (int s = 0; s < 9; ++s) {
        __syncthreads();                       // previous step's LDS reads done
        #pragma unroll
        for (int j = 0; j < 12; ++j) {
            int o = (w * 12 + j) * 1024;
            __builtin_amdgcn_global_load_lds(
                (const __attribute__((address_space(1))) void*)((const char*)wimg + (size_t)s * 49152 + o + l * 16),
                (__attribute__((address_space(3))) void*)(Wlds + o),
                16, 0, 0);
        }
        #pragma unroll
        for (int i = 0; i < 8; ++i) {
            int k2 = w + 4 * i;
            *reinterpret_cast<unsigned*>(Alds + l * 128 + ((4 * k2) ^ ((l & 7) << 4))) =
                pack2(xc[2 * i], xc[2 * i + 1]);
        }
        asm volatile("s_waitcnt vmcnt(0) lgkmcnt(0)" ::: "memory");
        __syncthreads();

        if (s < 8) loadx(s + 1, xn);           // lands under the MFMA below

        #pragma unroll
        for (int kc = 0; kc < 4; ++kc) {
            int cb_in = (kc * 32 + h * 16);
            sh8 a0 = *reinterpret_cast<const sh8*>(Alds + lq * 128        + (cb_in ^ key));
            sh8 a1 = *reinterpret_cast<const sh8*>(Alds + (lq + 32) * 128 + (cb_in ^ key));
            #pragma unroll
            for (int cb = 0; cb < 3; ++cb) {
                int col = w * 96 + cb * 32 + lq;
                sh8 wf = *reinterpret_cast<const sh8*>(Wlds + col * 128 + (cb_in ^ key));
                acc[0][cb] = __builtin_amdgcn_mfma_f32_32x32x16_bf16(a0, wf, acc[0][cb], 0, 0, 0);
                acc[1][cb] = __builtin_amdgcn_mfma_f32_32x32x16_bf16(a1, wf, acc[1][cb], 0, 0, 0);
            }
        }
        #pragma unroll
        for (int e = 0; e < 16; ++e) xc[e] = xn[e];
    }

    float* outT = (float*)Wlds;   // [64][132] fp32
    const int rix = tid >> 3;
    const int sub = tid & 7;
    #pragma unroll
    for (int t = 0; t < 3; ++t) {
        const float* bias = (t == 0) ? bq : (t == 1) ? bk : bv;
        const float* gg   = (t == 0) ? gq : (t == 1) ? gk : gv;
        const float* bb   = (t == 0) ? btq : (t == 1) ? btk : btv;
        __syncthreads();
        #pragma unroll
        for (int cb = 0; cb < 3; ++cb) {
            if (((w * 96 + cb * 32) >> 7) == t) {
                int cl = w * 96 + cb * 32 + lq - t * 128;
                float bv_ = bias[cl];
                #pragma unroll
                for (int mt = 0; mt < 2; ++mt)
                    #pragma unroll
                    for (int e = 0; e < 16; ++e) {
                        int row = mt * 32 + (e & 3) + 8 * (e >> 2) + 4 * h;
                        outT[row * 132 + cl] = acc[mt][cb][e] + bv_;
                    }
            }
        }
        __syncthreads();
        #pragma unroll
        for (int rh = 0; rh < 2; ++rh) {
            int row = rh * 32 + rix;
            float s1 = 0.f, s2 = 0.f;
            #pragma unroll
            for (int u = 0; u < 16; ++u) {
                float vv = outT[row * 132 + sub * 16 + u];
                s1 += vv; s2 += vv * vv;
            }
            #pragma unroll
            for (int off = 1; off < 8; off <<= 1) {
                s1 += __shfl_xor(s1, off);
                s2 += __shfl_xor(s2, off);
            }
            float mean = s1 * (1.f / 128.f);
            float var  = s2 * (1.f / 128.f) - mean * mean;
            float rstd = rsqrtf(var + EPS);
            if (t < 2) {
                float extra = (t == 0) ? QSCALE2 : 1.f;
                unsigned short* op = (t == 0 ? qo : ko) + (size_t)(b * N_ + n0 + row) * CO;
                #pragma unroll
                for (int u4 = 0; u4 < 4; ++u4) {
                    int c = sub * 16 + u4 * 4;
                    ushort4 o4;
                    o4.x = f2bf(((outT[row * 132 + c + 0] - mean) * rstd * gg[c + 0] + bb[c + 0]) * extra);
                    o4.y = f2bf(((outT[row * 132 + c + 1] - mean) * rstd * gg[c + 1] + bb[c + 1]) * extra);
                    o4.z = f2bf(((outT[row * 132 + c + 2] - mean) * rstd * gg[c + 2] + bb[c + 2]) * extra);
                    o4.w = f2bf(((outT[row * 132 + c + 3] - mean) * rstd * gg[c + 3] + bb[c + 3]) * extra);
                    *reinterpret_cast<ushort4*>(&op[c]) = o4;
                }
            } else {
                #pragma unroll
                for (int u = 0; u < 16; ++u) {
                    int c = sub * 16 + u;
                    outT[row * 132 + c] = (outT[row * 132 + c] - mean) * rstd * gg[c] + bb[c];
                }
            }
        }
        if (t == 2) {
            __syncthreads();
            int c = tid & 127, qs = tid >> 7;
            unsigned short* vp = vt + (size_t)(b * CO + c) * N_ + n0 + qs * 32;
            #pragma unroll
            for (int g4 = 0; g4 < 4; ++g4) {
                int r0 = qs * 32 + g4 * 8;
                uint4 wv;
                wv.x = pack2(outT[(r0 + 0) * 132 + c], outT[(r0 + 1) * 132 + c]);
                wv.y = pack2(outT[(r0 + 2) * 132 + c], outT[(r0 + 3) * 132 + c]);
                wv.z = pack2(outT[(r0 + 4) * 132 + c], outT[(r0 + 5) * 132 + c]);
                wv.w = pack2(outT[(r0 + 6) * 132 + c], outT[(r0 + 7) * 132 + c]);
                *reinterpret_cast<uint4*>(vp + g4 * 8) = wv;
            }
        }
    }
}

// ---------------- K2: MFMA flash attention — K-only LDS, V from L2 registers -------------
// grid 784: bid = nt*16 + kvh*8 + b. 4 waves = (qh = w&1) x (kv 32-half grp = w>>1).
// LDS: K buf0 [0,16K), K buf1 [16K,32K), ml @32K = 33.5 KB; VGPR<=168 -> 3 blocks/CU
// (12 waves/CU). V^T fragments are 16B global loads from L2 (parallel pipe to LDS);
// kc=0 fragments issue BEFORE stage(j+1) so waiting on them leaves the stage in flight.
__global__ __launch_bounds__(256, 3) void attn_kernel(
    const unsigned short* __restrict__ Qb, const unsigned short* __restrict__ Kb,
    const unsigned short* __restrict__ Vt,
    float* __restrict__ pacc0, float* __restrict__ pacc1, float* __restrict__ pml)
{
    __shared__ alignas(16) char LDS[33792];

    const int bid = blockIdx.x;
    const int b   = bid & 7;
    const int kvh = (bid >> 3) & 1;
    const int nt  = bid >> 4;
    const int n0  = nt * 64;
    const int tid = threadIdx.x;
    const int w   = tid >> 6;
    const int l   = tid & 63;
    const int h   = l >> 5;
    const int lq  = l & 31;
    const int qh  = w & 1;     // q-row half
    const int grp = w >> 1;    // kv 32-half within the 64-kv tile

    sh8 qr[8];
    {
        const unsigned short* qp = Qb + (size_t)(b * N_ + n0 + qh * 32 + lq) * CO + 8 * h;
        #pragma unroll
        for (int kc = 0; kc < 8; ++kc)
            qr[kc] = *reinterpret_cast<const sh8*>(qp + 16 * kc);
    }

    fx16 acc[4];
    #pragma unroll
    for (int mt = 0; mt < 4; ++mt)
        #pragma unroll
        for (int e = 0; e < 16; ++e) acc[mt][e] = 0.f;
    float m = -1e30f, ll = 0.f;

    const char* kgb = (const char*)(Kb + (size_t)b * N_ * CO);
    const unsigned short* vgb = Vt + (size_t)b * CO * N_;

    const int t0    = kvh * 25;
    const int ntile = 25 - kvh;            // kvh0: tiles [0,25); kvh1: [25,49)

    auto stage = [&](int ti, int bsel) {
        char* base = LDS + bsel * 16384;
        const int kb = ti * 64;
        #pragma unroll
        for (int j = 0; j < 4; ++j) {
            int cj  = w * 4 + j;                   // 0..15
            int o   = cj * 1024 + l * 16;
            int row = o >> 8;
            int ccK = (o & 255) ^ ((row & 15) << 4);
            __builtin_amdgcn_global_load_lds(
                (const __attribute__((address_space(1))) void*)(kgb + (size_t)(kb + row) * 256 + ccK),
                (__attribute__((address_space(3))) void*)(base + cj * 1024), 16, 0, 0);
        }
    };

    stage(t0, 0);
    asm volatile("s_waitcnt vmcnt(0)" ::: "memory");
    __syncthreads();

    for (int j = 0; j < ntile; ++j) {
        const int kb = (t0 + j) * 64;
        const unsigned short* vbase = vgb + kb + 32 * grp + 8 * h;   // + dd*N_ + 16*kc

        // ---- V kc=0 fragments (global/L2 -> regs); issued FIRST (oldest vmcnt slots) ----
        sh8 vf0[4];
        #pragma unroll
        for (int mt = 0; mt < 4; ++mt)
            vf0[mt] = *reinterpret_cast<const sh8*>(vbase + (size_t)(32 * mt + lq) * N_);

        if (j + 1 < ntile) stage(t0 + j + 1, (j + 1) & 1);   // prefetch flies under compute

        char* Kl = LDS + (j & 1) * 16384;

        // ---- QK^T (swapped), 2 independent MFMA chains ----
        fx16 sa, sb;
        #pragma unroll
        for (int e = 0; e < 16; ++e) { sa[e] = 0.f; sb[e] = 0.f; }
        const int r = 32 * grp + lq;
        const int rk = (r & 15) << 4;
        __builtin_amdgcn_s_setprio(1);
        #pragma unroll
        for (int kc = 0; kc < 4; ++kc) {
            sh8 a0 = *reinterpret_cast<const sh8*>(Kl + r * 256 + ((32 * kc + 16 * h) ^ rk));
            sh8 a1 = *reinterpret_cast<const sh8*>(Kl + r * 256 + ((32 * (kc + 4) + 16 * h) ^ rk));
            sa = __builtin_amdgcn_mfma_f32_32x32x16_bf16(a0, qr[kc],     sa, 0, 0, 0);
            sb = __builtin_amdgcn_mfma_f32_32x32x16_bf16(a1, qr[kc + 4], sb, 0, 0, 0);
        }
        __builtin_amdgcn_s_setprio(0);
        fx16 s_;
        #pragma unroll
        for (int e = 0; e < 16; ++e) s_[e] = sa[e] + sb[e];

        // ---- V kc=1 fragments: issue now, consumed after softmax + PV kc=0 ----
        sh8 vf1[4];
        #pragma unroll
        for (int mt = 0; mt < 4; ++mt)
            vf1[mt] = *reinterpret_cast<const sh8*>(vbase + (size_t)(32 * mt + lq) * N_ + 16);

        // ---- online softmax in exp2 domain, defer-max (THR=8) ----
        float pm = -1e30f;
        #pragma unroll
        for (int e = 0; e < 16; ++e) pm = fmaxf(pm, s_[e]);
        pm = fmaxf(pm, __shfl_xor(pm, 32));
        if (!__all(pm <= m + 8.f)) {
            float mn = fmaxf(m, pm);
            float sc = exp2v(m - mn);
            #pragma unroll
            for (int mt = 0; mt < 4; ++mt)
                #pragma unroll
                for (int e = 0; e < 16; ++e) acc[mt][e] *= sc;
            ll *= sc;
            m = mn;
        }
        float p[16];
        float rs = 0.f;
        #pragma unroll
        for (int e = 0; e < 16; ++e) {
            p[e] = exp2v(s_[e] - m); rs += p[e];
        }
        rs += __shfl_xor(rs, 32);
        ll += rs;

        // ---- T12: PV B-fragments in-register (cvt_pk + permlane32_swap) ----
        sh8 pf[2];
        #pragma unroll
        for (int kc = 0; kc < 2; ++kc) {
            const int er1 = 2 * kc;
            const int er2 = er1 + 1;
            unsigned a0_ = cvtpk(p[4 * er1 + 0], p[4 * er1 + 1]);
            unsigned a1_ = cvtpk(p[4 * er1 + 2], p[4 * er1 + 3]);
            unsigned b0_ = cvtpk(p[4 * er2 + 0], p[4 * er2 + 1]);
            unsigned b1_ = cvtpk(p[4 * er2 + 2], p[4 * er2 + 3]);
            asm("v_permlane32_swap_b32 %0, %1" : "+v"(a0_), "+v"(b0_));
            asm("v_permlane32_swap_b32 %0, %1" : "+v"(a1_), "+v"(b1_));
            ux4 pk; pk.x = a0_; pk.y = a1_; pk.z = b0_; pk.w = b1_;
            pf[kc] = __builtin_bit_cast(sh8, pk);
        }

        // ---- PV (swapped): ctx^T[d][q] += V^T(kv half) @ P^T — V from registers ----
        __builtin_amdgcn_s_setprio(1);
        #pragma unroll
        for (int mt = 0; mt < 4; ++mt)
            acc[mt] = __builtin_amdgcn_mfma_f32_32x32x16_bf16(vf0[mt], pf[0], acc[mt], 0, 0, 0);
        #pragma unroll
        for (int mt = 0; mt < 4; ++mt)
            acc[mt] = __builtin_amdgcn_mfma_f32_32x32x16_bf16(vf1[mt], pf[1], acc[mt], 0, 0, 0);
        __builtin_amdgcn_s_setprio(0);

        asm volatile("s_waitcnt vmcnt(0)" ::: "memory");   // K prefetch landed (hid under compute)
        __syncthreads();
    }

    // ---- in-block merge of the two kv-half partials (waves w and w^2) ----
    __syncthreads();
    float* ml = (float*)(LDS + 32768);
    if (h == 0) { ml[w * 32 + lq] = m; ml[128 + w * 32 + lq] = ll; }
    __syncthreads();
    float m_o = ml[(w ^ 2) * 32 + lq];
    float l_o = ml[128 + (w ^ 2) * 32 + lq];
    float mstar = fmaxf(m, m_o);
    float cs = exp2v(m - mstar);
    if (w >= 2) {
        float2* dst = (float2*)(LDS + (w - 2) * 16384);
        #pragma unroll
        for (int mt = 0; mt < 4; ++mt)
            #pragma unroll
            for (int e2 = 0; e2 < 8; ++e2)
                dst[(mt * 8 + e2) * 64 + l] =
                    make_float2(cs * acc[mt][2 * e2], cs * acc[mt][2 * e2 + 1]);
    }
    __syncthreads();
    if (w < 2) {
        float lf = cs * ll + exp2v(m_o - mstar) * l_o;
        const float2* src = (const float2*)(LDS + w * 16384);
        float2* bp = (float2*)((kvh ? pacc1 : pacc0) + (size_t)(b * 49 + nt) * 8192);
        #pragma unroll
        for (int mt = 0; mt < 4; ++mt)
            #pragma unroll
            for (int e2 = 0; e2 < 8; ++e2) {
                float2 v = src[(mt * 8 + e2) * 64 + l];
                v.x += cs * acc[mt][2 * e2];
                v.y += cs * acc[mt][2 * e2 + 1];
                bp[((qh * 4 + mt) * 8 + e2) * 64 + l] = v;
            }
        if (h == 0) {
            float* mlp = pml + (size_t)(kvh * 392 + b * 49 + nt) * 128;
            mlp[qh * 32 + lq]      = mstar;
            mlp[64 + qh * 32 + lq] = lf;
        }
    }
}

// ---------------- K3: merge partials + LN1 + GELU -> ctx, fused gate/BN tile partials ----
__global__ __launch_bounds__(128) void merge_kernel(
    const float* __restrict__ pacc0, const float* __restrict__ pacc1,
    const float* __restrict__ pml, const float* __restrict__ g1,
    const float* __restrict__ b1, const float* __restrict__ Wca,
    float* __restrict__ ctx,
    float* __restrict__ Gp, float* __restrict__ S1p, float* __restrict__ S2p)
{
    __shared__ alignas(16) char LDS[34304];   // 2x16KB Cb + g1s/b1s + wca
    const int bid = blockIdx.x;
    const int b   = bid & 7;
    const int nt  = bid >> 3;
    const int tile = b * 49 + nt;
    const int tid = threadIdx.x;
    const int w   = tid >> 6;      // qh
    const int l   = tid & 63;
    const int h   = l >> 5;
    const int lq  = l & 31;
    const int q   = w * 32 + lq;
    const int qx  = (lq & 7) << 4;

    float* g1s  = (float*)(LDS + 32768);
    float* b1s  = g1s + 128;
    float* wcas = b1s + 128;
    if (tid < 128) { g1s[tid] = g1[tid]; b1s[tid] = b1[tid]; }
    if (tid < 64)  wcas[tid] = Wca[nt * 64 + tid];

    float mA = pml[(size_t)tile * 128 + q];
    float lA = pml[(size_t)tile * 128 + 64 + q];
    float mB = pml[(size_t)(392 + tile) * 128 + q];
    float lB = pml[(size_t)(392 + tile) * 128 + 64 + q];
    float ms = fmaxf(mA, mB);
    float sA = exp2f(mA - ms), sB = exp2f(mB - ms);
    float lf = lA * sA + lB * sB;

    const float2* pa = (const float2*)(pacc0 + (size_t)tile * 8192);
    const float2* pb = (const float2*)(pacc1 + (size_t)tile * 8192);
    float acc[4][16];
    #pragma unroll
    for (int mt = 0; mt < 4; ++mt)
        #pragma unroll
        for (int e2 = 0; e2 < 8; ++e2) {
            float2 a = pa[((w * 4 + mt) * 8 + e2) * 64 + l];
            float2 bv = pb[((w * 4 + mt) * 8 + e2) * 64 + l];
            acc[mt][2 * e2]     = a.x * sA + bv.x * sB;
            acc[mt][2 * e2 + 1] = a.y * sA + bv.y * sB;
        }
    asm volatile("s_waitcnt vmcnt(0)" ::: "memory");
    __syncthreads();   // all reads of the cb tile done before any rewrite

    float inv = 1.f / lf;
    float s1 = 0.f, s2 = 0.f;
    #pragma unroll
    for (int mt = 0; mt < 4; ++mt)
        #pragma unroll
        for (int e = 0; e < 16; ++e) {
            float v = acc[mt][e] * inv;
            acc[mt][e] = v;
            s1 += v; s2 += v * v;
        }
    s1 += __shfl_xor(s1, 32);
    s2 += __shfl_xor(s2, 32);
    float mean = s1 * (1.f / 128.f);
    float var  = s2 * (1.f / 128.f) - mean * mean;
    float rstd = rsqrtf(var + EPS);

    char* Cb = LDS + w * 16384;   // 32x128 f32 staging, swizzled
    #pragma unroll
    for (int mt = 0; mt < 4; ++mt)
        #pragma unroll
        for (int e = 0; e < 16; e += 2) {
            int d = (e & 3) + 8 * (e >> 2) + 4 * h + 32 * mt;
            float2 pr;
            pr.x = gelu_exact((acc[mt][e]     - mean) * rstd * g1s[d]     + b1s[d]);
            pr.y = gelu_exact((acc[mt][e + 1] - mean) * rstd * g1s[d + 1] + b1s[d + 1]);
            *reinterpret_cast<float2*>(Cb + lq * 512 + ((d * 4) ^ qx)) = pr;
        }
    __syncthreads();   // whole 64x128 tile staged (both waves)

    // coalesced ctx write
    float* cg = ctx + (size_t)(b * N_ + nt * 64 + w * 32) * CO;
    #pragma unroll
    for (int rr = 0; rr < 4; ++rr) {
        int row = rr * 8 + (l >> 3);
        int cb0 = (l & 7) * 64;
        #pragma unroll
        for (int t = 0; t < 4; ++t) {
            float4 vv = *reinterpret_cast<const float4*>(
                Cb + row * 512 + ((cb0 + t * 16) ^ ((row & 7) << 4)));
            *reinterpret_cast<float4*>((char*)(cg + (size_t)row * CO) + cb0 + t * 16) = vv;
        }
    }

    // fused gate/BN tile partials: thread c sums the 64 rows of its column
    {
        int c = tid;   // 0..127
        float g = 0.f, t1 = 0.f, t2 = 0.f;
        #pragma unroll 8
        for (int r = 0; r < 64; ++r) {
            float v = *reinterpret_cast<const float*>(
                LDS + (r >> 5) * 16384 + (r & 31) * 512 + ((c * 4) ^ ((r & 7) << 4)));
            g  = fmaf(v, wcas[r], g);
            t1 += v;
            t2 = fmaf(v, v, t2);
        }
        size_t idx = (size_t)tile * 128 + c;
        Gp[idx] = g; S1p[idx] = t1; S2p[idx] = t2;
    }
}

// ---------------- K4: finalize gate + BN stats (256 threads, split over b) ----------------
__global__ __launch_bounds__(256) void bn_stats_kernel(
    const float* __restrict__ Gp, const float* __restrict__ S1p, const float* __restrict__ S2p,
    const float* __restrict__ bca, float* __restrict__ Gate,
    float* __restrict__ mu, float* __restrict__ rstd)
{
    __shared__ float redm[256], redq[256];
    const int tid = threadIdx.x;
    const int c  = tid & 127;
    const int hf = tid >> 7;
    float msum = 0, sqsum = 0;
    for (int bb = 0; bb < 4; ++bb) {
        int b = hf * 4 + bb;
        float g = 0, s1 = 0, s2 = 0;
        for (int t = 0; t < 49; ++t) {
            size_t idx = (size_t)(b * 49 + t) * 128 + c;
            g += Gp[idx]; s1 += S1p[idx]; s2 += S2p[idx];
        }
        g += bca[0];
        Gate[b * CO + c] = g;
        msum  = fmaf(g, s1, msum);
        sqsum = fmaf(g * g, s2, sqsum);
    }
    redm[tid] = msum; redq[tid] = sqsum;
    __syncthreads();
    if (hf == 0) {
        float mm = redm[c] + redm[c + 128];
        float qq = redq[c] + redq[c + 128];
        float mean = mm * (1.f / 25088.f);
        float var  = qq * (1.f / 25088.f) - mean * mean;
        mu[c] = mean;
        rstd[c] = rsqrtf(var + EPS);
    }
}

// ---------------- K5: transpose + gate + BN + GELU ----------------
__global__ __launch_bounds__(256) void out_kernel(
    const float* __restrict__ ctx, const float* __restrict__ Gate,
    const float* __restrict__ mu, const float* __restrict__ rstd,
    const float* __restrict__ bng, const float* __restrict__ bnb,
    float* __restrict__ out)
{
    __shared__ float T[32][33];
    const int nt = blockIdx.x, ct = blockIdx.y, b = blockIdx.z;
    const int n0 = nt * 32, c0 = ct * 32;
    const int tid = threadIdx.x;
    const int j = tid & 31, i0 = tid >> 5;
    #pragma unroll
    for (int p = 0; p < 4; ++p) {
        int i = i0 + p * 8;
        T[i][j] = ctx[(size_t)(b * N_ + n0 + i) * CO + c0 + j];
    }
    __syncthreads();
    #pragma unroll
    for (int p = 0; p < 4; ++p) {
        int cl = i0 + p * 8;
        int c = c0 + cl;
        float val = Gate[b * CO + c] * T[j][cl];
        val = (val - mu[c]) * rstd[c] * bng[c] + bnb[c];
        out[((size_t)(b * CO + c)) * N_ + n0 + j] = gelu_exact(val);
    }
}

extern "C" void kernel_launch(void* const* d_in, const int* in_sizes, int n_in,
                              void* d_out, int out_size, void* d_ws, size_t ws_size,
                              hipStream_t stream)
{
    const float* x   = (const float*)d_in[0];
    const float* Wq  = (const float*)d_in[1];
    const float* bq  = (const float*)d_in[2];
    const float* gq  = (const float*)d_in[3];
    const float* btq = (const float*)d_in[4];
    const float* Wk  = (const float*)d_in[5];
    const float* bk  = (const float*)d_in[6];
    const float* gk  = (const float*)d_in[7];
    const float* btk = (const float*)d_in[8];
    const float* Wv  = (const float*)d_in[9];
    const float* bv  = (const float*)d_in[10];
    const float* gv  = (const float*)d_in[11];
    const float* btv = (const float*)d_in[12];
    const float* g1  = (const float*)d_in[13];
    const float* b1  = (const float*)d_in[14];
    const float* Wca = (const float*)d_in[15];
    const float* bca = (const float*)d_in[16];
    const float* bng = (const float*)d_in[17];
    const float* bnb = (const float*)d_in[18];
    float* out = (float*)d_out;

    const size_t SZ = (size_t)B_ * N_ * CO;   // 3,211,264
    unsigned short* qb = (unsigned short*)d_ws;
    unsigned short* kb = qb + SZ;
    unsigned short* vt = kb + SZ;
    float* cb    = (float*)(vt + SZ);          // also kvh=0 partial (same tile layout)
    float* pacc1 = cb + SZ;                    // kvh=1 partials
    float* pml   = pacc1 + SZ;                 // 2*392*128 floats
    float* Gp    = pml + 100352;               // 392*128
    float* S1p   = Gp + 50176;
    float* S2p   = S1p + 50176;
    float* Gate  = S2p + 50176;
    float* muv   = Gate + 1024;
    float* rsv   = muv + 128;
    unsigned short* wimg = (unsigned short*)(rsv + 128);   // 442,368 B
    float* xpad = (float*)(wimg + 221184);                 // 8*64*58*58 floats

    pad_kernel<<<dim3(6728), 256, 0, stream>>>(x, xpad);
    wprep_kernel<<<dim3(432), 256, 0, stream>>>(Wq, Wk, Wv, wimg);
    qkv_kernel<<<dim3(392), 256, 0, stream>>>(xpad, wimg,
                                              bq, gq, btq, bk, gk, btk, bv, gv, btv,
                                              qb, kb, vt);
    attn_kernel<<<dim3(784), 256, 0, stream>>>(qb, kb, vt, cb, pacc1, pml);
    merge_kernel<<<dim3(392), 128, 0, stream>>>(cb, pacc1, pml, g1, b1, Wca,
                                                cb, Gp, S1p, S2p);
    bn_stats_kernel<<<dim3(1), 256, 0, stream>>>(Gp, S1p, S2p, bca, Gate, muv, rsv);
    out_kernel<<<dim3(98, 4, 8), 256, 0, stream>>>(cb, Gate, muv, rsv, bng, bnb, out);
}

// Round 14
// 143.981 us; speedup vs baseline: 1.6489x; 1.6489x over previous
//
#include <hip/hip_runtime.h>
#include <math.h>

#define B_   8
#define CIN  64
#define N_   3136
#define DIN  576
#define CO   128
#define EPS  1e-5f
// 1/sqrt(128) * log2(e): QK^T lands in log2 domain -> v_exp_f32 is exp2
#define QSCALE2 0.1275174447f

typedef __attribute__((ext_vector_type(8))) short sh8;     // 8 bf16 (4 VGPRs)
typedef __attribute__((ext_vector_type(16))) float fx16;   // MFMA 32x32 accum
typedef __attribute__((ext_vector_type(4))) unsigned int ux4;

__device__ __forceinline__ float gelu_exact(float x) {
    return 0.5f * x * (1.0f + erff(x * 0.7071067811865475f));
}
__device__ __forceinline__ unsigned short f2bf(float f) {   // RN-even f32->bf16
    unsigned u = __float_as_uint(f);
    u += 0x7fffu + ((u >> 16) & 1u);
    return (unsigned short)(u >> 16);
}
__device__ __forceinline__ unsigned pack2(float a, float b) {
    return (unsigned)f2bf(a) | ((unsigned)f2bf(b) << 16);
}
__device__ __forceinline__ unsigned cvtpk(float a, float b) {
    unsigned r;
    asm("v_cvt_pk_bf16_f32 %0, %1, %2" : "=v"(r) : "v"(a), "v"(b));
    return r;
}
__device__ __forceinline__ float exp2v(float x) {           // D = 2^S0
    float r;
    asm("v_exp_f32 %0, %1" : "=v"(r) : "v"(x));
    return r;
}

// ---------------- K0: fused prep — pad x AND pack W image (independent halves) ----------
__global__ __launch_bounds__(256) void prep_kernel(
    const float* __restrict__ x, float* __restrict__ xpad,
    const float* __restrict__ Wq, const float* __restrict__ Wk,
    const float* __restrict__ Wv, unsigned short* __restrict__ wimg)
{
    int bid = blockIdx.x;
    if (bid < 6728) {
        // x -> zero-padded image xpad[B][CIN][58][58]
        int id = bid * 256 + threadIdx.x;             // 1,722,368 elements
        int j  = id % 58;
        int i  = (id / 58) % 58;
        int bc = id / 3364;                           // b*64+c
        float v = 0.f;
        if (i >= 1 && i <= 56 && j >= 1 && j <= 56)
            v = x[((size_t)bc * 56 + (i - 1)) * 56 + (j - 1)];
        xpad[id] = v;
    } else {
        // Wq|Wk|Wv -> pre-swizzled bf16 image
        int id = (bid - 6728) * 256 + threadIdx.x;    // 110,592 u32 elements
        int col = id % 384;
        int k2  = id / 384;
        int k   = 2 * k2;
        int s   = k >> 6;
        int kk  = k & 63;
        int t   = col >> 7, c = col & 127;
        const float* W = (t == 0) ? Wq : (t == 1) ? Wk : Wv;
        float v0 = W[(size_t)k * CO + c];
        float v1 = W[(size_t)(k + 1) * CO + c];
        char* dst = (char*)wimg + (size_t)s * 49152 + col * 128 + ((kk * 2) ^ ((col & 7) << 4));
        *reinterpret_cast<unsigned*>(dst) = pack2(v0, v1);
    }
}

// ---------------- K1: im2col + QKV MFMA GEMM + bias + LayerNorm -> bf16 ----------------
__global__ __launch_bounds__(256, 2) void qkv_kernel(
    const float* __restrict__ xpad, const unsigned short* __restrict__ wimg,
    const float* __restrict__ bq, const float* __restrict__ gq, const float* __restrict__ btq,
    const float* __restrict__ bk, const float* __restrict__ gk, const float* __restrict__ btk,
    const float* __restrict__ bv, const float* __restrict__ gv, const float* __restrict__ btv,
    unsigned short* __restrict__ qo, unsigned short* __restrict__ ko,
    unsigned short* __restrict__ vt)
{
    __shared__ alignas(16) char Alds[8192];    // [64 rows][64 k] bf16, swizzled
    __shared__ alignas(16) char Wlds[49152];   // [384 cols][64 k] bf16, swizzled image
    const int b   = blockIdx.x & 7;
    const int n0  = (blockIdx.x >> 3) * 64;
    const int tid = threadIdx.x;
    const int w   = tid >> 6;
    const int l   = tid & 63;
    const int h   = l >> 5;
    const int lq  = l & 31;
    const int key = (lq & 7) << 4;

    const int n  = n0 + l;
    const int oh = n / 56, ow = n - 56 * oh;
    const int xbase = b * CIN * 3364 + oh * 58 + ow;   // + c*3364 + kh*58 + kw

    fx16 acc[2][3];
    #pragma unroll
    for (int mt = 0; mt < 2; ++mt)
        #pragma unroll
        for (int cb = 0; cb < 3; ++cb)
            #pragma unroll
            for (int e = 0; e < 16; ++e) acc[mt][cb][e] = 0.f;

    float xc[16], xn[16];

    auto loadx = [&](int s, float* xv) {
        #pragma unroll
        for (int i = 0; i < 8; ++i) {
            int k2 = w + 4 * i;
            int d0 = s * 64 + 2 * k2, d1 = d0 + 1;
            int c0 = d0 / 9, r90 = d0 - 9 * c0;
            int kh0 = r90 / 3, kw0 = r90 - 3 * kh0;
            int c1 = d1 / 9, r91 = d1 - 9 * c1;
            int kh1 = r91 / 3, kw1 = r91 - 3 * kh1;
            xv[2 * i]     = xpad[xbase + c0 * 3364 + kh0 * 58 + kw0];
            xv[2 * i + 1] = xpad[xbase + c1 * 3364 + kh1 * 58 + kw1];
        }
    };

    loadx(0, xc);
    for (int s = 0; s < 9; ++s) {
        __syncthreads();                       // previous step's LDS reads done
        #pragma unroll
        for (int j = 0; j < 12; ++j) {
            int o = (w * 12 + j) * 1024;
            __builtin_amdgcn_global_load_lds(
                (const __attribute__((address_space(1))) void*)((const char*)wimg + (size_t)s * 49152 + o + l * 16),
                (__attribute__((address_space(3))) void*)(Wlds + o),
                16, 0, 0);
        }
        #pragma unroll
        for (int i = 0; i < 8; ++i) {
            int k2 = w + 4 * i;
            *reinterpret_cast<unsigned*>(Alds + l * 128 + ((4 * k2) ^ ((l & 7) << 4))) =
                pack2(xc[2 * i], xc[2 * i + 1]);
        }
        asm volatile("s_waitcnt vmcnt(0) lgkmcnt(0)" ::: "memory");
        __syncthreads();

        if (s < 8) loadx(s + 1, xn);           // lands under the MFMA below

        #pragma unroll
        for (int kc = 0; kc < 4; ++kc) {
            int cb_in = (kc * 32 + h * 16);
            sh8 a0 = *reinterpret_cast<const sh8*>(Alds + lq * 128        + (cb_in ^ key));
            sh8 a1 = *reinterpret_cast<const sh8*>(Alds + (lq + 32) * 128 + (cb_in ^ key));
            #pragma unroll
            for (int cb = 0; cb < 3; ++cb) {
                int col = w * 96 + cb * 32 + lq;
                sh8 wf = *reinterpret_cast<const sh8*>(Wlds + col * 128 + (cb_in ^ key));
                acc[0][cb] = __builtin_amdgcn_mfma_f32_32x32x16_bf16(a0, wf, acc[0][cb], 0, 0, 0);
                acc[1][cb] = __builtin_amdgcn_mfma_f32_32x32x16_bf16(a1, wf, acc[1][cb], 0, 0, 0);
            }
        }
        #pragma unroll
        for (int e = 0; e < 16; ++e) xc[e] = xn[e];
    }

    float* outT = (float*)Wlds;   // [64][132] fp32
    const int rix = tid >> 3;
    const int sub = tid & 7;
    #pragma unroll
    for (int t = 0; t < 3; ++t) {
        const float* bias = (t == 0) ? bq : (t == 1) ? bk : bv;
        const float* gg   = (t == 0) ? gq : (t == 1) ? gk : gv;
        const float* bb   = (t == 0) ? btq : (t == 1) ? btk : btv;
        __syncthreads();
        #pragma unroll
        for (int cb = 0; cb < 3; ++cb) {
            if (((w * 96 + cb * 32) >> 7) == t) {
                int cl = w * 96 + cb * 32 + lq - t * 128;
                float bv_ = bias[cl];
                #pragma unroll
                for (int mt = 0; mt < 2; ++mt)
                    #pragma unroll
                    for (int e = 0; e < 16; ++e) {
                        int row = mt * 32 + (e & 3) + 8 * (e >> 2) + 4 * h;
                        outT[row * 132 + cl] = acc[mt][cb][e] + bv_;
                    }
            }
        }
        __syncthreads();
        #pragma unroll
        for (int rh = 0; rh < 2; ++rh) {
            int row = rh * 32 + rix;
            float s1 = 0.f, s2 = 0.f;
            #pragma unroll
            for (int u = 0; u < 16; ++u) {
                float vv = outT[row * 132 + sub * 16 + u];
                s1 += vv; s2 += vv * vv;
            }
            #pragma unroll
            for (int off = 1; off < 8; off <<= 1) {
                s1 += __shfl_xor(s1, off);
                s2 += __shfl_xor(s2, off);
            }
            float mean = s1 * (1.f / 128.f);
            float var  = s2 * (1.f / 128.f) - mean * mean;
            float rstd = rsqrtf(var + EPS);
            if (t < 2) {
                float extra = (t == 0) ? QSCALE2 : 1.f;
                unsigned short* op = (t == 0 ? qo : ko) + (size_t)(b * N_ + n0 + row) * CO;
                #pragma unroll
                for (int u4 = 0; u4 < 4; ++u4) {
                    int c = sub * 16 + u4 * 4;
                    ushort4 o4;
                    o4.x = f2bf(((outT[row * 132 + c + 0] - mean) * rstd * gg[c + 0] + bb[c + 0]) * extra);
                    o4.y = f2bf(((outT[row * 132 + c + 1] - mean) * rstd * gg[c + 1] + bb[c + 1]) * extra);
                    o4.z = f2bf(((outT[row * 132 + c + 2] - mean) * rstd * gg[c + 2] + bb[c + 2]) * extra);
                    o4.w = f2bf(((outT[row * 132 + c + 3] - mean) * rstd * gg[c + 3] + bb[c + 3]) * extra);
                    *reinterpret_cast<ushort4*>(&op[c]) = o4;
                }
            } else {
                #pragma unroll
                for (int u = 0; u < 16; ++u) {
                    int c = sub * 16 + u;
                    outT[row * 132 + c] = (outT[row * 132 + c] - mean) * rstd * gg[c] + bb[c];
                }
            }
        }
        if (t == 2) {
            __syncthreads();
            int c = tid & 127, qs = tid >> 7;
            unsigned short* vp = vt + (size_t)(b * CO + c) * N_ + n0 + qs * 32;
            #pragma unroll
            for (int g4 = 0; g4 < 4; ++g4) {
                int r0 = qs * 32 + g4 * 8;
                uint4 wv;
                wv.x = pack2(outT[(r0 + 0) * 132 + c], outT[(r0 + 1) * 132 + c]);
                wv.y = pack2(outT[(r0 + 2) * 132 + c], outT[(r0 + 3) * 132 + c]);
                wv.z = pack2(outT[(r0 + 4) * 132 + c], outT[(r0 + 5) * 132 + c]);
                wv.w = pack2(outT[(r0 + 6) * 132 + c], outT[(r0 + 7) * 132 + c]);
                *reinterpret_cast<uint4*>(vp + g4 * 8) = wv;
            }
        }
    }
}

// ---------------- K2: MFMA flash attention, full-KV fused epilogue ----------------------
// grid 392: bid -> b = bid&7 (XCD-affine), nt = bid>>3. 4 waves = (qh = w&1) x (grp = w>>1).
// LDS: buf0 [0,32K) = K|V, buf1 [32K,64K), ml @64K, g1s/b1s/wcas after. 2 blocks/CU.
// Pipeline: stage(j+1) BEFORE compute(j); vmcnt(0)+barrier AFTER compute (r10 structure).
// Epilogue: in-block grp merge -> LN1+GELU -> swizzled LDS staging -> coalesced ctx write
// + fused gate/BN column partials (former merge_kernel, now in-kernel).
__global__ __launch_bounds__(256, 2) void attn_kernel(
    const unsigned short* __restrict__ Qb, const unsigned short* __restrict__ Kb,
    const unsigned short* __restrict__ Vt,
    const float* __restrict__ g1, const float* __restrict__ b1,
    const float* __restrict__ Wca, float* __restrict__ ctx,
    float* __restrict__ Gp, float* __restrict__ S1p, float* __restrict__ S2p)
{
    __shared__ alignas(16) char LDS[67840];

    const int bid = blockIdx.x;
    const int b   = bid & 7;
    const int nt  = bid >> 3;          // 0..48
    const int n0  = nt * 64;
    const int tid = threadIdx.x;
    const int w   = tid >> 6;
    const int l   = tid & 63;
    const int h   = l >> 5;
    const int lq  = l & 31;
    const int qh  = w & 1;     // q-row half
    const int grp = w >> 1;    // kv 32-half within the 64-kv tile
    const int qx  = (lq & 7) << 4;

    float* ml   = (float*)(LDS + 65536);   // 256 floats
    float* g1s  = ml + 256;
    float* b1s  = g1s + 128;
    float* wcas = b1s + 128;
    if (tid < 128) { g1s[tid] = g1[tid]; b1s[tid] = b1[tid]; }
    if (tid < 64)  wcas[tid] = Wca[nt * 64 + tid];

    sh8 qr[8];
    {
        const unsigned short* qp = Qb + (size_t)(b * N_ + n0 + qh * 32 + lq) * CO + 8 * h;
        #pragma unroll
        for (int kc = 0; kc < 8; ++kc)
            qr[kc] = *reinterpret_cast<const sh8*>(qp + 16 * kc);
    }

    fx16 acc[4];
    #pragma unroll
    for (int mt = 0; mt < 4; ++mt)
        #pragma unroll
        for (int e = 0; e < 16; ++e) acc[mt][e] = 0.f;
    float m = -1e30f, ll = 0.f;

    const char* kgb = (const char*)(Kb + (size_t)b * N_ * CO);
    const char* vgb = (const char*)(Vt + (size_t)b * CO * N_);

    auto stage = [&](int ti, int bsel) {
        char* base = LDS + bsel * 32768;
        const int kb = ti * 64;
        #pragma unroll
        for (int j = 0; j < 4; ++j) {
            int cj  = w * 4 + j;                   // 0..15
            int o   = cj * 1024 + l * 16;
            int row = o >> 8;
            int ccK = (o & 255) ^ ((row & 15) << 4);
            int d   = o >> 7;
            int ccV = (o & 127) ^ ((d & 7) << 4);
            __builtin_amdgcn_global_load_lds(
                (const __attribute__((address_space(1))) void*)(kgb + (size_t)(kb + row) * 256 + ccK),
                (__attribute__((address_space(3))) void*)(base + cj * 1024), 16, 0, 0);
            __builtin_amdgcn_global_load_lds(
                (const __attribute__((address_space(1))) void*)(vgb + ((size_t)d * N_ + kb) * 2 + ccV),
                (__attribute__((address_space(3))) void*)(base + 16384 + cj * 1024), 16, 0, 0);
        }
    };

    stage(0, 0);
    asm volatile("s_waitcnt vmcnt(0)" ::: "memory");
    __syncthreads();

    for (int j = 0; j < 49; ++j) {
        if (j + 1 < 49) stage(j + 1, (j + 1) & 1);   // prefetch flies under compute

        char* Kl = LDS + (j & 1) * 32768;
        char* Vl = Kl + 16384;

        // ---- QK^T (swapped), 2 independent MFMA chains ----
        fx16 sa, sb;
        #pragma unroll
        for (int e = 0; e < 16; ++e) { sa[e] = 0.f; sb[e] = 0.f; }
        const int r = 32 * grp + lq;
        const int rk = (r & 15) << 4;
        __builtin_amdgcn_s_setprio(1);
        #pragma unroll
        for (int kc = 0; kc < 4; ++kc) {
            sh8 a0 = *reinterpret_cast<const sh8*>(Kl + r * 256 + ((32 * kc + 16 * h) ^ rk));
            sh8 a1 = *reinterpret_cast<const sh8*>(Kl + r * 256 + ((32 * (kc + 4) + 16 * h) ^ rk));
            sa = __builtin_amdgcn_mfma_f32_32x32x16_bf16(a0, qr[kc],     sa, 0, 0, 0);
            sb = __builtin_amdgcn_mfma_f32_32x32x16_bf16(a1, qr[kc + 4], sb, 0, 0, 0);
        }
        __builtin_amdgcn_s_setprio(0);
        fx16 s_;
        #pragma unroll
        for (int e = 0; e < 16; ++e) s_[e] = sa[e] + sb[e];

        // ---- online softmax in exp2 domain, defer-max (THR=8) ----
        float pm = -1e30f;
        #pragma unroll
        for (int e = 0; e < 16; ++e) pm = fmaxf(pm, s_[e]);
        pm = fmaxf(pm, __shfl_xor(pm, 32));
        if (!__all(pm <= m + 8.f)) {
            float mn = fmaxf(m, pm);
            float sc = exp2v(m - mn);
            #pragma unroll
            for (int mt = 0; mt < 4; ++mt)
                #pragma unroll
                for (int e = 0; e < 16; ++e) acc[mt][e] *= sc;
            ll *= sc;
            m = mn;
        }
        float p[16];
        float rs = 0.f;
        #pragma unroll
        for (int e = 0; e < 16; ++e) {
            p[e] = exp2v(s_[e] - m); rs += p[e];
        }
        rs += __shfl_xor(rs, 32);
        ll += rs;

        // ---- T12: PV B-fragments in-register (cvt_pk + permlane32_swap) ----
        sh8 pf[2];
        #pragma unroll
        for (int kc = 0; kc < 2; ++kc) {
            const int er1 = 2 * kc;
            const int er2 = er1 + 1;
            unsigned a0_ = cvtpk(p[4 * er1 + 0], p[4 * er1 + 1]);
            unsigned a1_ = cvtpk(p[4 * er1 + 2], p[4 * er1 + 3]);
            unsigned b0_ = cvtpk(p[4 * er2 + 0], p[4 * er2 + 1]);
            unsigned b1_ = cvtpk(p[4 * er2 + 2], p[4 * er2 + 3]);
            asm("v_permlane32_swap_b32 %0, %1" : "+v"(a0_), "+v"(b0_));
            asm("v_permlane32_swap_b32 %0, %1" : "+v"(a1_), "+v"(b1_));
            ux4 pk; pk.x = a0_; pk.y = a1_; pk.z = b0_; pk.w = b1_;
            pf[kc] = __builtin_bit_cast(sh8, pk);
        }

        // ---- PV (swapped): ctx^T[d][q] += V^T(kv half) @ P^T ----
        __builtin_amdgcn_s_setprio(1);
        #pragma unroll
        for (int kc = 0; kc < 2; ++kc) {
            #pragma unroll
            for (int mt = 0; mt < 4; ++mt) {
                int dd = 32 * mt + lq;
                sh8 vf = *reinterpret_cast<const sh8*>(
                    Vl + dd * 128 + ((64 * grp + 32 * kc + 16 * h) ^ ((dd & 7) << 4)));
                acc[mt] = __builtin_amdgcn_mfma_f32_32x32x16_bf16(vf, pf[kc], acc[mt], 0, 0, 0);
            }
        }
        __builtin_amdgcn_s_setprio(0);

        asm volatile("s_waitcnt vmcnt(0)" ::: "memory");   // prefetch landed (hid under compute)
        __syncthreads();
    }

    // ---- in-block merge of the two kv-half partials (waves w and w^2) ----
    if (h == 0) { ml[w * 32 + lq] = m; ml[128 + w * 32 + lq] = ll; }
    __syncthreads();
    float m_o = ml[(w ^ 2) * 32 + lq];
    float l_o = ml[128 + (w ^ 2) * 32 + lq];
    float mstar = fmaxf(m, m_o);
    float cs = exp2v(m - mstar);
    if (w >= 2) {
        float2* dst = (float2*)(LDS + (w - 2) * 16384);
        #pragma unroll
        for (int mt = 0; mt < 4; ++mt)
            #pragma unroll
            for (int e2 = 0; e2 < 8; ++e2)
                dst[(mt * 8 + e2) * 64 + l] =
                    make_float2(cs * acc[mt][2 * e2], cs * acc[mt][2 * e2 + 1]);
    }
    __syncthreads();
    if (w < 2) {
        float lf = cs * ll + exp2v(m_o - mstar) * l_o;
        const float2* src = (const float2*)(LDS + w * 16384);
        #pragma unroll
        for (int mt = 0; mt < 4; ++mt)
            #pragma unroll
            for (int e2 = 0; e2 < 8; ++e2) {
                float2 v = src[(mt * 8 + e2) * 64 + l];
                acc[mt][2 * e2]     = cs * acc[mt][2 * e2]     + v.x;
                acc[mt][2 * e2 + 1] = cs * acc[mt][2 * e2 + 1] + v.y;
            }

        // ---- epilogue: 1/l, fused LN over d + GELU, swizzled staging ----
        float inv = 1.f / lf;
        float s1 = 0.f, s2 = 0.f;
        #pragma unroll
        for (int mt = 0; mt < 4; ++mt)
            #pragma unroll
            for (int e = 0; e < 16; ++e) {
                float v = acc[mt][e] * inv;
                acc[mt][e] = v;
                s1 += v; s2 += v * v;
            }
        s1 += __shfl_xor(s1, 32);
        s2 += __shfl_xor(s2, 32);
        float mean = s1 * (1.f / 128.f);
        float var  = s2 * (1.f / 128.f) - mean * mean;
        float rstd = rsqrtf(var + EPS);

        char* Cb = LDS + 32768 + w * 16384;   // wave-private 32x128 f32 staging
        #pragma unroll
        for (int mt = 0; mt < 4; ++mt)
            #pragma unroll
            for (int e = 0; e < 16; e += 2) {
                int d = (e & 3) + 8 * (e >> 2) + 4 * h + 32 * mt;
                float2 pr;
                pr.x = gelu_exact((acc[mt][e]     - mean) * rstd * g1s[d]     + b1s[d]);
                pr.y = gelu_exact((acc[mt][e + 1] - mean) * rstd * g1s[d + 1] + b1s[d + 1]);
                *reinterpret_cast<float2*>(Cb + lq * 512 + ((d * 4) ^ qx)) = pr;
            }
    }
    __syncthreads();   // whole 64x128 tile staged (both slabs)

    if (w < 2) {
        // coalesced ctx write (own slab)
        char* Cb = LDS + 32768 + w * 16384;
        float* cg = ctx + (size_t)(b * N_ + n0 + w * 32) * CO;
        #pragma unroll
        for (int rr = 0; rr < 4; ++rr) {
            int row = rr * 8 + (l >> 3);
            int cb0 = (l & 7) * 64;
            #pragma unroll
            for (int t = 0; t < 4; ++t) {
                float4 vv = *reinterpret_cast<const float4*>(
                    Cb + row * 512 + ((cb0 + t * 16) ^ ((row & 7) << 4)));
                *reinterpret_cast<float4*>((char*)(cg + (size_t)row * CO) + cb0 + t * 16) = vv;
            }
        }
        // fused gate/BN tile partials: thread c sums the 64 rows of its column
        int c = tid;   // 0..127
        float g = 0.f, t1 = 0.f, t2 = 0.f;
        #pragma unroll 8
        for (int rr = 0; rr < 64; ++rr) {
            float v = *reinterpret_cast<const float*>(
                LDS + 32768 + (rr >> 5) * 16384 + (rr & 31) * 512 + ((c * 4) ^ ((rr & 7) << 4)));
            g  = fmaf(v, wcas[rr], g);
            t1 += v;
            t2 = fmaf(v, v, t2);
        }
        size_t idx = (size_t)(b * 49 + nt) * 128 + c;
        Gp[idx] = g; S1p[idx] = t1; S2p[idx] = t2;
    }
}

// ---------------- K4: finalize gate + BN stats (256 threads, split over b) ----------------
__global__ __launch_bounds__(256) void bn_stats_kernel(
    const float* __restrict__ Gp, const float* __restrict__ S1p, const float* __restrict__ S2p,
    const float* __restrict__ bca, float* __restrict__ Gate,
    float* __restrict__ mu, float* __restrict__ rstd)
{
    __shared__ float redm[256], redq[256];
    const int tid = threadIdx.x;
    const int c  = tid & 127;
    const int hf = tid >> 7;
    float msum = 0, sqsum = 0;
    for (int bb = 0; bb < 4; ++bb) {
        int b = hf * 4 + bb;
        float g = 0, s1 = 0, s2 = 0;
        for (int t = 0; t < 49; ++t) {
            size_t idx = (size_t)(b * 49 + t) * 128 + c;
            g += Gp[idx]; s1 += S1p[idx]; s2 += S2p[idx];
        }
        g += bca[0];
        Gate[b * CO + c] = g;
        msum  = fmaf(g, s1, msum);
        sqsum = fmaf(g * g, s2, sqsum);
    }
    redm[tid] = msum; redq[tid] = sqsum;
    __syncthreads();
    if (hf == 0) {
        float mm = redm[c] + redm[c + 128];
        float qq = redq[c] + redq[c + 128];
        float mean = mm * (1.f / 25088.f);
        float var  = qq * (1.f / 25088.f) - mean * mean;
        mu[c] = mean;
        rstd[c] = rsqrtf(var + EPS);
    }
}

// ---------------- K5: transpose + gate + BN + GELU ----------------
__global__ __launch_bounds__(256) void out_kernel(
    const float* __restrict__ ctx, const float* __restrict__ Gate,
    const float* __restrict__ mu, const float* __restrict__ rstd,
    const float* __restrict__ bng, const float* __restrict__ bnb,
    float* __restrict__ out)
{
    __shared__ float T[32][33];
    const int nt = blockIdx.x, ct = blockIdx.y, b = blockIdx.z;
    const int n0 = nt * 32, c0 = ct * 32;
    const int tid = threadIdx.x;
    const int j = tid & 31, i0 = tid >> 5;
    #pragma unroll
    for (int p = 0; p < 4; ++p) {
        int i = i0 + p * 8;
        T[i][j] = ctx[(size_t)(b * N_ + n0 + i) * CO + c0 + j];
    }
    __syncthreads();
    #pragma unroll
    for (int p = 0; p < 4; ++p) {
        int cl = i0 + p * 8;
        int c = c0 + cl;
        float val = Gate[b * CO + c] * T[j][cl];
        val = (val - mu[c]) * rstd[c] * bng[c] + bnb[c];
        out[((size_t)(b * CO + c)) * N_ + n0 + j] = gelu_exact(val);
    }
}

extern "C" void kernel_launch(void* const* d_in, const int* in_sizes, int n_in,
                              void* d_out, int out_size, void* d_ws, size_t ws_size,
                              hipStream_t stream)
{
    const float* x   = (const float*)d_in[0];
    const float* Wq  = (const float*)d_in[1];
    const float* bq  = (const float*)d_in[2];
    const float* gq  = (const float*)d_in[3];
    const float* btq = (const float*)d_in[4];
    const float* Wk  = (const float*)d_in[5];
    const float* bk  = (const float*)d_in[6];
    const float* gk  = (const float*)d_in[7];
    const float* btk = (const float*)d_in[8];
    const float* Wv  = (const float*)d_in[9];
    const float* bv  = (const float*)d_in[10];
    const float* gv  = (const float*)d_in[11];
    const float* btv = (const float*)d_in[12];
    const float* g1  = (const float*)d_in[13];
    const float* b1  = (const float*)d_in[14];
    const float* Wca = (const float*)d_in[15];
    const float* bca = (const float*)d_in[16];
    const float* bng = (const float*)d_in[17];
    const float* bnb = (const float*)d_in[18];
    float* out = (float*)d_out;

    const size_t SZ = (size_t)B_ * N_ * CO;   // 3,211,264
    unsigned short* qb = (unsigned short*)d_ws;
    unsigned short* kb = qb + SZ;
    unsigned short* vt = kb + SZ;
    float* cb   = (float*)(vt + SZ);
    float* Gp   = cb + SZ;                     // 392*128
    float* S1p  = Gp + 50176;
    float* S2p  = S1p + 50176;
    float* Gate = S2p + 50176;
    float* muv  = Gate + 1024;
    float* rsv  = muv + 128;
    unsigned short* wimg = (unsigned short*)(rsv + 128);   // 442,368 B
    float* xpad = (float*)(wimg + 221184);                 // 8*64*58*58 floats

    prep_kernel<<<dim3(7160), 256, 0, stream>>>(x, xpad, Wq, Wk, Wv, wimg);
    qkv_kernel<<<dim3(392), 256, 0, stream>>>(xpad, wimg,
                                              bq, gq, btq, bk, gk, btk, bv, gv, btv,
                                              qb, kb, vt);
    attn_kernel<<<dim3(392), 256, 0, stream>>>(qb, kb, vt, g1, b1, Wca,
                                               cb, Gp, S1p, S2p);
    bn_stats_kernel<<<dim3(1), 256, 0, stream>>>(Gp, S1p, S2p, bca, Gate, muv, rsv);
    out_kernel<<<dim3(98, 4, 8), 256, 0, stream>>>(cb, Gate, muv, rsv, bng, bnb, out);
}